// Round 15
// baseline (104.852 us; speedup 1.0000x reference)
//
#include <hip/hip_runtime.h>
#include <hip/hip_bf16.h>
#include <math.h>

typedef __attribute__((ext_vector_type(4))) float f32x4;
typedef __attribute__((ext_vector_type(8))) short bf16x8;

#define N_TOK 8192
#define D_IN  1024
#define H_DIM 256
#define S_SPLIT 16
#define QSCALE 0.09016844f   // log2(e)/sqrt(256)

static __device__ __forceinline__ float bf2f(unsigned short u) {
  return __uint_as_float(((unsigned)u) << 16);
}
static __device__ __forceinline__ float fast_exp2(float x) {
  float e;
  asm("v_exp_f32 %0, %1" : "=v"(e) : "v"(x));
  return e;
}
static __device__ __forceinline__ void gload_lds16(const void* g, void* l) {
  __builtin_amdgcn_global_load_lds(
      (const __attribute__((address_space(1))) void*)g,
      (__attribute__((address_space(3))) void*)l, 16, 0, 0);
}
#define QLOAD(dst, base, off) \
  asm volatile("global_load_dwordx4 %0, %1, off offset:" #off \
               : "=v"(dst) : "v"(base))

// ---------------- prep: weight casts + wv2 (8-way parallel) + bv2 ----------------
__global__ __launch_bounds__(256) void prep_kernel(
    const float* __restrict__ w1, const float* __restrict__ qw,
    const float* __restrict__ kw, const float* __restrict__ vw,
    const float* __restrict__ vb, const float* __restrict__ w2,
    __hip_bfloat16* __restrict__ w1b, __hip_bfloat16* __restrict__ qwb,
    __hip_bfloat16* __restrict__ kwb, float* __restrict__ wv2, float* __restrict__ bv2)
{
  int b = blockIdx.x, tid = threadIdx.x;
  if (b < 384) {
    const float* in; __hip_bfloat16* out; int base;
    if (b < 256)      { in = w1; out = w1b; base = b; }
    else if (b < 320) { in = qw; out = qwb; base = b - 256; }
    else              { in = kw; out = kwb; base = b - 320; }
    int i = base * 1024 + tid * 4;
    float4 v = *reinterpret_cast<const float4*>(in + i);
    union { __hip_bfloat16 h[4]; ushort4 u; } cv;
    cv.h[0] = __float2bfloat16(v.x);
    cv.h[1] = __float2bfloat16(v.y);
    cv.h[2] = __float2bfloat16(v.z);
    cv.h[3] = __float2bfloat16(v.w);
    *reinterpret_cast<ushort4*>(out + i) = cv.u;
    return;
  }
  if (b < 392) {
    __shared__ float sw2b[256];
    __shared__ float red2[8][32];
    sw2b[tid] = w2[tid];
    __syncthreads();
    const int jb = (b - 384) * 32;
    const int jj = tid & 31, cg = tid >> 5;
    float a = 0.f;
    #pragma unroll 8
    for (int c = cg * 32; c < cg * 32 + 32; ++c)
      a = fmaf(vw[c * 256 + jb + jj], sw2b[c], a);
    red2[cg][jj] = a;
    __syncthreads();
    if (tid < 32) {
      float s = 0.f;
      #pragma unroll
      for (int g = 0; g < 8; ++g) s += red2[g][tid];
      wv2[jb + tid] = s;
    }
    return;
  }
  __shared__ float red[256];
  red[tid] = vb[tid] * w2[tid];
  __syncthreads();
  for (int s = 128; s > 0; s >>= 1) {
    if (tid < s) red[tid] += red[tid + s];
    __syncthreads();
  }
  if (tid == 0) bv2[0] = red[0];
}

// ---------------- front v5: register-batched, ONE barrier ----------------
// 256 blocks x 32 rows, 512 thr (8 waves: wr=w>>2 row-16-half, wc=w&3 col-64-group).
// P1: h = x@W1^T + b1 -- 8 K-chunks of 128; per chunk 8 xf32x4 + 16 W-frag loads
//     batched to regs (one MLP burst), 16 MFMAs. No LDS staging, no barriers.
// h -> swizzled LDS; ONE __syncthreads.
// P2: q (waves 0-3) / k (waves 4-7), 2 K-halves, 16 W-frags + 8 h-reads per half.
// P3: both rowdots per wave (4 rows each).
__global__ __launch_bounds__(512) void front_kernel(
    const float* __restrict__ x, const __hip_bfloat16* __restrict__ W1,
    const __hip_bfloat16* __restrict__ Wq, const __hip_bfloat16* __restrict__ Wk,
    const float* __restrict__ b1, const float* __restrict__ bq, const float* __restrict__ bk,
    const float* __restrict__ w2, const float* __restrict__ wv2, const float* __restrict__ b2,
    __hip_bfloat16* __restrict__ Qo, __hip_bfloat16* __restrict__ Ko,
    float* __restrict__ hw2, float* __restrict__ vs)
{
  __shared__ __attribute__((aligned(16))) unsigned char h_lds[32 * 512];  // 16KB
  const int tid = threadIdx.x;
  const int w = tid >> 6, l = tid & 63, r16 = l & 15, kg = l >> 4;
  const int wr = w >> 2, wc = w & 3;
  const int rowbase = blockIdx.x * 32;
  const int rsw8 = (r16 & 7) << 4;

  // ---- P1 ----
  {
    const char* xb  = (const char*)(x + (size_t)(rowbase + wr * 16 + r16) * D_IN);
    const char* w1r = (const char*)W1;

    f32x4 acc[4];
    #pragma unroll
    for (int c = 0; c < 4; ++c) acc[c] = (f32x4){0.f, 0.f, 0.f, 0.f};

    for (int chunk = 0; chunk < 8; ++chunk) {
      f32x4 xa[8];
      #pragma unroll
      for (int ks = 0; ks < 4; ++ks) {
        xa[2 * ks]     = *reinterpret_cast<const f32x4*>(xb + chunk * 512 + ks * 128 + kg * 32);
        xa[2 * ks + 1] = *reinterpret_cast<const f32x4*>(xb + chunk * 512 + ks * 128 + kg * 32 + 16);
      }
      bf16x8 bw[4][4];
      #pragma unroll
      for (int ks = 0; ks < 4; ++ks)
        #pragma unroll
        for (int c = 0; c < 4; ++c)
          bw[ks][c] = *reinterpret_cast<const bf16x8*>(
              w1r + (size_t)(wc * 64 + c * 16 + r16) * 2048 + chunk * 256 + ks * 64 + kg * 16);
      #pragma unroll
      for (int ks = 0; ks < 4; ++ks) {
        union { __hip_bfloat16 h[8]; bf16x8 v; } af;
        #pragma unroll
        for (int e = 0; e < 4; ++e) {
          af.h[e]     = __float2bfloat16(xa[2 * ks][e]);
          af.h[4 + e] = __float2bfloat16(xa[2 * ks + 1][e]);
        }
        #pragma unroll
        for (int c = 0; c < 4; ++c)
          acc[c] = __builtin_amdgcn_mfma_f32_16x16x32_bf16(af.v, bw[ks][c], acc[c], 0, 0, 0);
      }
    }

    // h (+bias) -> swizzled LDS
    #pragma unroll
    for (int c = 0; c < 4; ++c) {
      int col = wc * 64 + c * 16 + r16;
      float bs = b1[col];
      #pragma unroll
      for (int j = 0; j < 4; ++j) {
        int row = wr * 16 + kg * 4 + j;
        *reinterpret_cast<__hip_bfloat16*>(
            &h_lds[row * 512 + ((col * 2) ^ ((row & 7) << 4))]) =
            __float2bfloat16(acc[c][j] + bs);
      }
    }
  }
  __syncthreads();   // the only barrier

  // ---- P2: q/k projections ----
  {
    const bool isq = (w < 4);
    const char* Wp = (const char*)(isq ? Wq : Wk);
    const int cb = (w & 3) * 64;

    f32x4 qacc[2][4];
    #pragma unroll
    for (int rt = 0; rt < 2; ++rt)
      #pragma unroll
      for (int c = 0; c < 4; ++c) qacc[rt][c] = (f32x4){0.f, 0.f, 0.f, 0.f};

    #pragma unroll
    for (int half = 0; half < 2; ++half) {
      bf16x8 bw2[4][4];
      #pragma unroll
      for (int ks = 0; ks < 4; ++ks)
        #pragma unroll
        for (int c = 0; c < 4; ++c)
          bw2[ks][c] = *reinterpret_cast<const bf16x8*>(
              Wp + (size_t)(cb + c * 16 + r16) * 512 + half * 256 + ks * 64 + kg * 16);
      bf16x8 af2[2][4];
      #pragma unroll
      for (int rt = 0; rt < 2; ++rt)
        #pragma unroll
        for (int ks = 0; ks < 4; ++ks)
          af2[rt][ks] = *reinterpret_cast<const bf16x8*>(
              &h_lds[(rt * 16 + r16) * 512 + ((half * 256 + ks * 64 + kg * 16) ^ rsw8)]);
      #pragma unroll
      for (int ks = 0; ks < 4; ++ks)
        #pragma unroll
        for (int c = 0; c < 4; ++c) {
          qacc[0][c] = __builtin_amdgcn_mfma_f32_16x16x32_bf16(af2[0][ks], bw2[ks][c], qacc[0][c], 0, 0, 0);
          qacc[1][c] = __builtin_amdgcn_mfma_f32_16x16x32_bf16(af2[1][ks], bw2[ks][c], qacc[1][c], 0, 0, 0);
        }
    }

    const float* bp = isq ? bq : bk;
    const float scl = isq ? QSCALE : 1.f;
    __hip_bfloat16* Op = isq ? Qo : Ko;
    #pragma unroll
    for (int rt = 0; rt < 2; ++rt)
      #pragma unroll
      for (int c = 0; c < 4; ++c) {
        int col = cb + c * 16 + r16;
        float bb = bp[col];
        #pragma unroll
        for (int j = 0; j < 4; ++j) {
          int row = rowbase + rt * 16 + kg * 4 + j;
          Op[(size_t)row * H_DIM + col] = __float2bfloat16((qacc[rt][c][j] + bb) * scl);
        }
      }
  }

  // ---- P3: both rowdots, wave w -> rows w*4..w*4+3 ----
  {
    const int c16 = l & 15;
    const int row = w * 4 + (l >> 4);
    const int rs2 = (row & 7) << 4;
    bf16x8 h0 = *reinterpret_cast<const bf16x8*>(&h_lds[row * 512 + ((c16 * 32) ^ rs2)]);
    bf16x8 h1 = *reinterpret_cast<const bf16x8*>(&h_lds[row * 512 + ((c16 * 32 + 16) ^ rs2)]);
    float s2 = 0.f, sv = 0.f;
    #pragma unroll
    for (int i = 0; i < 8; ++i) {
      float hv = bf2f((unsigned short)h0[i]);
      s2 += hv * w2[c16 * 16 + i];
      sv += hv * wv2[c16 * 16 + i];
    }
    #pragma unroll
    for (int i = 0; i < 8; ++i) {
      float hv = bf2f((unsigned short)h1[i]);
      s2 += hv * w2[c16 * 16 + 8 + i];
      sv += hv * wv2[c16 * 16 + 8 + i];
    }
    #pragma unroll
    for (int off = 1; off < 16; off <<= 1) {
      s2 += __shfl_xor(s2, off);
      sv += __shfl_xor(sv, off);
    }
    if (c16 == 0) {
      hw2[rowbase + row] = s2 + b2[0];
      vs[rowbase + row]  = sv;
    }
  }
}

// ---------------- attention partials (R13 verbatim: plateau 42us) ----------------
#define KVBLK 64
#define KRANGE (N_TOK / S_SPLIT)   // 512 rows per split
__global__ __launch_bounds__(256, 2) void attn_partial_kernel(
    const __hip_bfloat16* __restrict__ Q, const __hip_bfloat16* __restrict__ K,
    const float* __restrict__ vsg, float* __restrict__ pden, float* __restrict__ pacc)
{
  __shared__ __attribute__((aligned(16))) unsigned char ktile[2][KVBLK * 512];
  __shared__ float vs_lds[KRANGE];

  const int tid = threadIdx.x;
  const int w   = tid >> 6;
  const int l   = tid & 63;
  const int r16 = l & 15;
  const int kg  = l >> 4;
  const int split   = blockIdx.y;
  const int mstart  = split * KRANGE;
  const int rowbase = blockIdx.x * 256 + w * 64;

  if (tid < KRANGE / 4)
    *reinterpret_cast<float4*>(vs_lds + tid * 4) =
        *reinterpret_cast<const float4*>(vsg + mstart + tid * 4);

  bf16x8 qf[4][8];
  #pragma unroll
  for (int sub = 0; sub < 4; ++sub) {
    const char* qp = (const char*)(Q + (size_t)(rowbase + sub * 16 + r16) * H_DIM + kg * 8);
    QLOAD(qf[sub][0], qp, 0);
    QLOAD(qf[sub][1], qp, 64);
    QLOAD(qf[sub][2], qp, 128);
    QLOAD(qf[sub][3], qp, 192);
    QLOAD(qf[sub][4], qp, 256);
    QLOAD(qf[sub][5], qp, 320);
    QLOAD(qf[sub][6], qp, 384);
    QLOAD(qf[sub][7], qp, 448);
  }
  asm volatile("s_waitcnt vmcnt(0)" ::: "memory");

  const int trow = tid >> 5;
  const int tbsw = ((tid & 31) * 16) ^ ((trow & 7) << 4);
  const char* kbase = (const char*)K + (size_t)(mstart + trow) * 512 + tbsw;
  const int ldst = trow * 512 + (tid & 31) * 16;

  const int rsw = (r16 & 7) << 4;
  const int cb  = kg * 16;

  float den[4][4], acc[4][4];
  #pragma unroll
  for (int sub = 0; sub < 4; ++sub)
    #pragma unroll
    for (int j = 0; j < 4; ++j) { den[sub][j] = 0.f; acc[sub][j] = 0.f; }

  #pragma unroll
  for (int i = 0; i < 8; ++i)
    gload_lds16(kbase + (size_t)(i * 8) * 512, &ktile[0][i * 4096 + ldst]);
  __syncthreads();

  const int NT = KRANGE / KVBLK;   // 8
  for (int t = 0; t < NT; ++t) {
    const int cur = t & 1;
    if (t + 1 < NT) {
      #pragma unroll
      for (int i = 0; i < 8; ++i)
        gload_lds16(kbase + (size_t)((t + 1) * KVBLK + i * 8) * 512,
                    &ktile[cur ^ 1][i * 4096 + ldst]);
    }

    const unsigned char* kt = &ktile[cur][0];
    #pragma unroll
    for (int h = 0; h < 2; ++h) {
      f32x4 d[4][2];
      #pragma unroll
      for (int sub = 0; sub < 4; ++sub)
        #pragma unroll
        for (int n = 0; n < 2; ++n) d[sub][n] = (f32x4){0.f, 0.f, 0.f, 0.f};

      __builtin_amdgcn_s_setprio(1);
      #pragma unroll
      for (int n = 0; n < 2; ++n) {
        const int row = h * 32 + n * 16 + r16;
        #pragma unroll
        for (int kk = 0; kk < 8; ++kk) {
          bf16x8 b = *reinterpret_cast<const bf16x8*>(
              kt + row * 512 + ((kk * 64 + cb) ^ rsw));
          d[0][n] = __builtin_amdgcn_mfma_f32_16x16x32_bf16(qf[0][kk], b, d[0][n], 0, 0, 0);
          d[1][n] = __builtin_amdgcn_mfma_f32_16x16x32_bf16(qf[1][kk], b, d[1][n], 0, 0, 0);
          d[2][n] = __builtin_amdgcn_mfma_f32_16x16x32_bf16(qf[2][kk], b, d[2][n], 0, 0, 0);
          d[3][n] = __builtin_amdgcn_mfma_f32_16x16x32_bf16(qf[3][kk], b, d[3][n], 0, 0, 0);
        }
      }
      __builtin_amdgcn_s_setprio(0);

      const float vsm0 = vs_lds[t * KVBLK + h * 32 + r16];
      const float vsm1 = vs_lds[t * KVBLK + h * 32 + 16 + r16];
      #pragma unroll
      for (int sub = 0; sub < 4; ++sub)
        #pragma unroll
        for (int j = 0; j < 4; ++j) {
          float e0 = fast_exp2(d[sub][0][j]);
          float e1 = fast_exp2(d[sub][1][j]);
          den[sub][j] += e0 + e1;
          acc[sub][j] = fmaf(e0, vsm0, fmaf(e1, vsm1, acc[sub][j]));
        }
    }
    __syncthreads();
  }

  #pragma unroll
  for (int sub = 0; sub < 4; ++sub)
    #pragma unroll
    for (int j = 0; j < 4; ++j) {
      #pragma unroll
      for (int off = 1; off < 16; off <<= 1) {
        den[sub][j] += __shfl_xor(den[sub][j], off);
        acc[sub][j] += __shfl_xor(acc[sub][j], off);
      }
    }
  if (r16 == 0) {
    #pragma unroll
    for (int sub = 0; sub < 4; ++sub)
      #pragma unroll
      for (int j = 0; j < 4; ++j) {
        int row = rowbase + sub * 16 + kg * 4 + j;
        pden[split * N_TOK + row] = den[sub][j];
        pacc[split * N_TOK + row] = acc[sub][j];
      }
  }
}

// ---------------- merge splits + residual ----------------
__global__ __launch_bounds__(256) void combine_kernel(
    const float* __restrict__ pden, const float* __restrict__ pacc,
    const float* __restrict__ hw2, const float* __restrict__ bv2, float* __restrict__ out)
{
  int r = blockIdx.x * 256 + threadIdx.x;
  float den = 0.f, acc = 0.f;
  #pragma unroll
  for (int s = 0; s < S_SPLIT; ++s) {
    den += pden[s * N_TOK + r];
    acc += pacc[s * N_TOK + r];
  }
  out[r] = hw2[r] + acc / den + bv2[0];
}

extern "C" void kernel_launch(void* const* d_in, const int* in_sizes, int n_in,
                              void* d_out, int out_size, void* d_ws, size_t ws_size,
                              hipStream_t stream) {
  const float* x      = (const float*)d_in[0];
  const float* lin1_w = (const float*)d_in[1];
  const float* lin1_b = (const float*)d_in[2];
  const float* q_w    = (const float*)d_in[3];
  const float* q_b    = (const float*)d_in[4];
  const float* k_w    = (const float*)d_in[5];
  const float* k_b    = (const float*)d_in[6];
  const float* v_w    = (const float*)d_in[7];
  const float* v_b    = (const float*)d_in[8];
  const float* lin2_w = (const float*)d_in[9];
  const float* lin2_b = (const float*)d_in[10];
  float* out = (float*)d_out;

  char* ws = (char*)d_ws;
  size_t off = 0;
  auto alloc = [&](size_t bytes) {
    char* p = ws + off;
    off += (bytes + 255) & ~(size_t)255;
    return p;
  };
  __hip_bfloat16* w1b = (__hip_bfloat16*)alloc((size_t)H_DIM * D_IN * 2);
  __hip_bfloat16* qwb = (__hip_bfloat16*)alloc((size_t)H_DIM * H_DIM * 2);
  __hip_bfloat16* kwb = (__hip_bfloat16*)alloc((size_t)H_DIM * H_DIM * 2);
  __hip_bfloat16* qb  = (__hip_bfloat16*)alloc((size_t)N_TOK * H_DIM * 2);
  __hip_bfloat16* kb  = (__hip_bfloat16*)alloc((size_t)N_TOK * H_DIM * 2);
  float* hw2  = (float*)alloc((size_t)N_TOK * 4);
  float* vsv  = (float*)alloc((size_t)N_TOK * 4);
  float* wv2  = (float*)alloc((size_t)H_DIM * 4);
  float* bv2  = (float*)alloc(256);
  float* pden = (float*)alloc((size_t)S_SPLIT * N_TOK * 4);
  float* pacc = (float*)alloc((size_t)S_SPLIT * N_TOK * 4);
  (void)ws_size; (void)in_sizes; (void)n_in; (void)out_size;

  prep_kernel<<<393, 256, 0, stream>>>(lin1_w, q_w, k_w, v_w, v_b, lin2_w,
                                       w1b, qwb, kwb, wv2, bv2);

  front_kernel<<<N_TOK / 32, 512, 0, stream>>>(x, w1b, qwb, kwb, lin1_b, q_b, k_b,
                                               lin2_w, wv2, lin2_b, qb, kb, hw2, vsv);

  attn_partial_kernel<<<dim3(32, S_SPLIT), 256, 0, stream>>>(qb, kb, vsv, pden, pacc);

  combine_kernel<<<N_TOK / 256, 256, 0, stream>>>(pden, pacc, hw2, bv2, out);
}

// Round 16
// 76.625 us; speedup vs baseline: 1.3684x; 1.3684x over previous
//
#include <hip/hip_runtime.h>
#include <hip/hip_bf16.h>
#include <math.h>

typedef __attribute__((ext_vector_type(4))) float f32x4;
typedef __attribute__((ext_vector_type(8))) short bf16x8;

#define N_TOK 8192
#define D_IN  1024
#define H_DIM 256
#define S_SPLIT 16
#define QSCALE 0.09016844f   // log2(e)/sqrt(256)

static __device__ __forceinline__ float bf2f(unsigned short u) {
  return __uint_as_float(((unsigned)u) << 16);
}
static __device__ __forceinline__ float fast_exp2(float x) {
  float e;
  asm("v_exp_f32 %0, %1" : "=v"(e) : "v"(x));
  return e;
}
static __device__ __forceinline__ void gload_lds16(const void* g, void* l) {
  __builtin_amdgcn_global_load_lds(
      (const __attribute__((address_space(1))) void*)g,
      (__attribute__((address_space(3))) void*)l, 16, 0, 0);
}
#define QLOAD(dst, base, off) \
  asm volatile("global_load_dwordx4 %0, %1, off offset:" #off \
               : "=v"(dst) : "v"(base))

// ---------------- prep: weight casts + wv2 (8-way parallel) + bv2 ----------------
__global__ __launch_bounds__(256) void prep_kernel(
    const float* __restrict__ w1, const float* __restrict__ qw,
    const float* __restrict__ kw, const float* __restrict__ vw,
    const float* __restrict__ vb, const float* __restrict__ w2,
    __hip_bfloat16* __restrict__ w1b, __hip_bfloat16* __restrict__ qwb,
    __hip_bfloat16* __restrict__ kwb, float* __restrict__ wv2, float* __restrict__ bv2)
{
  int b = blockIdx.x, tid = threadIdx.x;
  if (b < 384) {
    const float* in; __hip_bfloat16* out; int base;
    if (b < 256)      { in = w1; out = w1b; base = b; }
    else if (b < 320) { in = qw; out = qwb; base = b - 256; }
    else              { in = kw; out = kwb; base = b - 320; }
    int i = base * 1024 + tid * 4;
    float4 v = *reinterpret_cast<const float4*>(in + i);
    union { __hip_bfloat16 h[4]; ushort4 u; } cv;
    cv.h[0] = __float2bfloat16(v.x);
    cv.h[1] = __float2bfloat16(v.y);
    cv.h[2] = __float2bfloat16(v.z);
    cv.h[3] = __float2bfloat16(v.w);
    *reinterpret_cast<ushort4*>(out + i) = cv.u;
    return;
  }
  if (b < 392) {
    __shared__ float sw2b[256];
    __shared__ float red2[8][32];
    sw2b[tid] = w2[tid];
    __syncthreads();
    const int jb = (b - 384) * 32;
    const int jj = tid & 31, cg = tid >> 5;
    float a = 0.f;
    #pragma unroll 8
    for (int c = cg * 32; c < cg * 32 + 32; ++c)
      a = fmaf(vw[c * 256 + jb + jj], sw2b[c], a);
    red2[cg][jj] = a;
    __syncthreads();
    if (tid < 32) {
      float s = 0.f;
      #pragma unroll
      for (int g = 0; g < 8; ++g) s += red2[g][tid];
      wv2[jb + tid] = s;
    }
    return;
  }
  __shared__ float red[256];
  red[tid] = vb[tid] * w2[tid];
  __syncthreads();
  for (int s = 128; s > 0; s >>= 1) {
    if (tid < s) red[tid] += red[tid + s];
    __syncthreads();
  }
  if (tid == 0) bv2[0] = red[0];
}

// ---------------- front (R12 verbatim -- proven best, gload_lds staged) ----------------
__global__ __launch_bounds__(512) void front_kernel(
    const float* __restrict__ x, const __hip_bfloat16* __restrict__ W1,
    const __hip_bfloat16* __restrict__ Wq, const __hip_bfloat16* __restrict__ Wk,
    const float* __restrict__ b1, const float* __restrict__ bq, const float* __restrict__ bk,
    const float* __restrict__ w2, const float* __restrict__ wv2, const float* __restrict__ b2,
    __hip_bfloat16* __restrict__ Qo, __hip_bfloat16* __restrict__ Ko,
    float* __restrict__ hw2, float* __restrict__ vs)
{
  __shared__ __attribute__((aligned(16))) unsigned char h_lds[16384];
  __shared__ __attribute__((aligned(16))) unsigned char sbuf[2][36864];
  const int tid = threadIdx.x;
  const int w = tid >> 6, l = tid & 63, r16 = l & 15, kg = l >> 4;
  const int wr = w >> 2, wc = w & 3;
  const int rowbase = blockIdx.x * 32;
  const int rsw = (r16 & 7) << 4;

  const int xrow = tid >> 4, xc = tid & 15;
  const float* xsrc = x + (size_t)(rowbase + xrow) * D_IN + xc * 4;
  const int xdst = xrow * 128 + ((xc * 8) ^ ((xrow & 7) << 4));
  const char* W1b = (const char*)W1;

  f32x4 acc[4];
  #pragma unroll
  for (int c = 0; c < 4; ++c) acc[c] = (f32x4){0.f, 0.f, 0.f, 0.f};

  {
    f32x4 xv = *reinterpret_cast<const f32x4*>(xsrc);
    #pragma unroll
    for (int i = 0; i < 4; ++i) {
      int p = i * 8192 + tid * 16;
      int col = p >> 7, bb = p & 127;
      gload_lds16(W1b + (size_t)col * 2048 + (bb ^ ((col & 7) << 4)), &sbuf[0][4096 + p]);
    }
    union { __hip_bfloat16 h[4]; ushort4 u; } cv;
    cv.h[0] = __float2bfloat16(xv[0]); cv.h[1] = __float2bfloat16(xv[1]);
    cv.h[2] = __float2bfloat16(xv[2]); cv.h[3] = __float2bfloat16(xv[3]);
    *reinterpret_cast<ushort4*>(&sbuf[0][xdst]) = cv.u;
  }
  __syncthreads();

  for (int t = 0; t < 16; ++t) {
    const int cur = t & 1;
    f32x4 xv;
    if (t + 1 < 16) {
      xv = *reinterpret_cast<const f32x4*>(xsrc + (t + 1) * 64);
      const int k0b = (t + 1) * 128;
      #pragma unroll
      for (int i = 0; i < 4; ++i) {
        int p = i * 8192 + tid * 16;
        int col = p >> 7, bb = p & 127;
        gload_lds16(W1b + (size_t)col * 2048 + k0b + (bb ^ ((col & 7) << 4)),
                    &sbuf[cur ^ 1][4096 + p]);
      }
    }
    const unsigned char* A = &sbuf[cur][0];
    const unsigned char* W = &sbuf[cur][4096];
    #pragma unroll
    for (int ks = 0; ks < 2; ++ks) {
      bf16x8 a = *reinterpret_cast<const bf16x8*>(
          A + (wr * 16 + r16) * 128 + ((ks * 64 + kg * 16) ^ rsw));
      #pragma unroll
      for (int c = 0; c < 4; ++c) {
        const int colloc = wc * 64 + c * 16 + r16;
        bf16x8 b = *reinterpret_cast<const bf16x8*>(
            W + colloc * 128 + ((ks * 64 + kg * 16) ^ rsw));
        acc[c] = __builtin_amdgcn_mfma_f32_16x16x32_bf16(a, b, acc[c], 0, 0, 0);
      }
    }
    if (t + 1 < 16) {
      union { __hip_bfloat16 h[4]; ushort4 u; } cv;
      cv.h[0] = __float2bfloat16(xv[0]); cv.h[1] = __float2bfloat16(xv[1]);
      cv.h[2] = __float2bfloat16(xv[2]); cv.h[3] = __float2bfloat16(xv[3]);
      *reinterpret_cast<ushort4*>(&sbuf[cur ^ 1][xdst]) = cv.u;
    }
    __syncthreads();
  }

  #pragma unroll
  for (int c = 0; c < 4; ++c) {
    int col = wc * 64 + c * 16 + r16;
    float bs = b1[col];
    #pragma unroll
    for (int j = 0; j < 4; ++j) {
      int row = wr * 16 + kg * 4 + j;
      *reinterpret_cast<__hip_bfloat16*>(
          &h_lds[row * 512 + ((col * 2) ^ ((row & 7) << 4))]) =
          __float2bfloat16(acc[c][j] + bs);
    }
  }

  const char* wqB = (const char*)Wq;
  const char* wkB = (const char*)Wk;
  #pragma unroll
  for (int i = 0; i < 4; ++i) {
    int p = i * 8192 + tid * 16;
    int col = p >> 7, bb = p & 127;
    gload_lds16(wqB + (size_t)col * 512 + (bb ^ ((col & 7) << 4)), &sbuf[0][p]);
  }
  __syncthreads();

  f32x4 qacc[4];
  #pragma unroll
  for (int c = 0; c < 4; ++c) qacc[c] = (f32x4){0.f, 0.f, 0.f, 0.f};

  for (int r = 0; r < 8; ++r) {
    const int buf = r & 1;
    if (r + 1 < 8) {
      const char* Wsel = (r + 1 < 4) ? wqB : wkB;
      const int kq1 = (r + 1) & 3;
      #pragma unroll
      for (int i = 0; i < 4; ++i) {
        int p = i * 8192 + tid * 16;
        int col = p >> 7, bb = p & 127;
        gload_lds16(Wsel + (size_t)col * 512 + kq1 * 128 + (bb ^ ((col & 7) << 4)),
                    &sbuf[buf ^ 1][p]);
      }
    }
    const int kq = r & 3;
    const unsigned char* WT = &sbuf[buf][0];
    #pragma unroll
    for (int ks = 0; ks < 2; ++ks) {
      bf16x8 a = *reinterpret_cast<const bf16x8*>(
          &h_lds[(wr * 16 + r16) * 512 + ((kq * 128 + ks * 64 + kg * 16) ^ rsw)]);
      #pragma unroll
      for (int c = 0; c < 4; ++c) {
        const int colloc = wc * 64 + c * 16 + r16;
        bf16x8 b = *reinterpret_cast<const bf16x8*>(
            WT + colloc * 128 + ((ks * 64 + kg * 16) ^ rsw));
        qacc[c] = __builtin_amdgcn_mfma_f32_16x16x32_bf16(a, b, qacc[c], 0, 0, 0);
      }
    }
    if (r == 3) {
      #pragma unroll
      for (int c = 0; c < 4; ++c) {
        int col = wc * 64 + c * 16 + r16;
        float bb = bq[col];
        #pragma unroll
        for (int j = 0; j < 4; ++j) {
          int row = rowbase + wr * 16 + kg * 4 + j;
          Qo[(size_t)row * H_DIM + col] = __float2bfloat16((qacc[c][j] + bb) * QSCALE);
        }
        qacc[c] = (f32x4){0.f, 0.f, 0.f, 0.f};
      }
    }
    __syncthreads();
  }
  #pragma unroll
  for (int c = 0; c < 4; ++c) {
    int col = wc * 64 + c * 16 + r16;
    float bb = bk[col];
    #pragma unroll
    for (int j = 0; j < 4; ++j) {
      int row = rowbase + wr * 16 + kg * 4 + j;
      Ko[(size_t)row * H_DIM + col] = __float2bfloat16(qacc[c][j] + bb);
    }
  }

  {
    const bool isw2 = (w < 4);
    const float* wsel = isw2 ? w2 : wv2;
    const int c16 = l & 15;
    #pragma unroll
    for (int pass = 0; pass < 2; ++pass) {
      int row = (w & 3) * 8 + pass * 4 + (l >> 4);
      int rs2 = (row & 7) << 4;
      bf16x8 h0 = *reinterpret_cast<const bf16x8*>(&h_lds[row * 512 + ((c16 * 32) ^ rs2)]);
      bf16x8 h1 = *reinterpret_cast<const bf16x8*>(&h_lds[row * 512 + ((c16 * 32 + 16) ^ rs2)]);
      float s = 0.f;
      #pragma unroll
      for (int i = 0; i < 8; ++i) s += bf2f((unsigned short)h0[i]) * wsel[c16 * 16 + i];
      #pragma unroll
      for (int i = 0; i < 8; ++i) s += bf2f((unsigned short)h1[i]) * wsel[c16 * 16 + 8 + i];
      #pragma unroll
      for (int off = 1; off < 16; off <<= 1) s += __shfl_xor(s, off);
      if (c16 == 0) {
        if (isw2) hw2[rowbase + row] = s + b2[0];
        else      vs[rowbase + row]  = s;
      }
    }
  }
}

// ---------------- attention partials: both-halves MFMA region, batched exp tail ----------------
// Same R13 staging/geometry; change: d[2][4][2] keeps BOTH halves live so the
// MFMA stream is one 256-inst region (under one setprio bracket) and the 64 exps
// run as one tail -- role-split lets the co-resident wave's MFMA cover exp.
#define KVBLK 64
#define KRANGE (N_TOK / S_SPLIT)   // 512 rows per split
__global__ __launch_bounds__(256, 2) void attn_partial_kernel(
    const __hip_bfloat16* __restrict__ Q, const __hip_bfloat16* __restrict__ K,
    const float* __restrict__ vsg, float* __restrict__ pden, float* __restrict__ pacc)
{
  __shared__ __attribute__((aligned(16))) unsigned char ktile[2][KVBLK * 512];
  __shared__ float vs_lds[KRANGE];

  const int tid = threadIdx.x;
  const int w   = tid >> 6;
  const int l   = tid & 63;
  const int r16 = l & 15;
  const int kg  = l >> 4;
  const int split   = blockIdx.y;
  const int mstart  = split * KRANGE;
  const int rowbase = blockIdx.x * 256 + w * 64;

  if (tid < KRANGE / 4)
    *reinterpret_cast<float4*>(vs_lds + tid * 4) =
        *reinterpret_cast<const float4*>(vsg + mstart + tid * 4);

  bf16x8 qf[4][8];
  #pragma unroll
  for (int sub = 0; sub < 4; ++sub) {
    const char* qp = (const char*)(Q + (size_t)(rowbase + sub * 16 + r16) * H_DIM + kg * 8);
    QLOAD(qf[sub][0], qp, 0);
    QLOAD(qf[sub][1], qp, 64);
    QLOAD(qf[sub][2], qp, 128);
    QLOAD(qf[sub][3], qp, 192);
    QLOAD(qf[sub][4], qp, 256);
    QLOAD(qf[sub][5], qp, 320);
    QLOAD(qf[sub][6], qp, 384);
    QLOAD(qf[sub][7], qp, 448);
  }
  asm volatile("s_waitcnt vmcnt(0)" ::: "memory");

  const int trow = tid >> 5;
  const int tbsw = ((tid & 31) * 16) ^ ((trow & 7) << 4);
  const char* kbase = (const char*)K + (size_t)(mstart + trow) * 512 + tbsw;
  const int ldst = trow * 512 + (tid & 31) * 16;

  const int rsw = (r16 & 7) << 4;
  const int cb  = kg * 16;

  float den[4][4], acc[4][4];
  #pragma unroll
  for (int sub = 0; sub < 4; ++sub)
    #pragma unroll
    for (int j = 0; j < 4; ++j) { den[sub][j] = 0.f; acc[sub][j] = 0.f; }

  #pragma unroll
  for (int i = 0; i < 8; ++i)
    gload_lds16(kbase + (size_t)(i * 8) * 512, &ktile[0][i * 4096 + ldst]);
  __syncthreads();

  const int NT = KRANGE / KVBLK;   // 8
  for (int t = 0; t < NT; ++t) {
    const int cur = t & 1;
    if (t + 1 < NT) {
      #pragma unroll
      for (int i = 0; i < 8; ++i)
        gload_lds16(kbase + (size_t)((t + 1) * KVBLK + i * 8) * 512,
                    &ktile[cur ^ 1][i * 4096 + ldst]);
    }

    const unsigned char* kt = &ktile[cur][0];
    f32x4 d[2][4][2];
    #pragma unroll
    for (int h = 0; h < 2; ++h)
      #pragma unroll
      for (int sub = 0; sub < 4; ++sub)
        #pragma unroll
        for (int n = 0; n < 2; ++n) d[h][sub][n] = (f32x4){0.f, 0.f, 0.f, 0.f};

    // one long MFMA region: both halves, 256 MFMAs, no VALU interleaved
    __builtin_amdgcn_s_setprio(1);
    #pragma unroll
    for (int h = 0; h < 2; ++h) {
      #pragma unroll
      for (int n = 0; n < 2; ++n) {
        const int row = h * 32 + n * 16 + r16;
        #pragma unroll
        for (int kk = 0; kk < 8; ++kk) {
          bf16x8 b = *reinterpret_cast<const bf16x8*>(
              kt + row * 512 + ((kk * 64 + cb) ^ rsw));
          d[h][0][n] = __builtin_amdgcn_mfma_f32_16x16x32_bf16(qf[0][kk], b, d[h][0][n], 0, 0, 0);
          d[h][1][n] = __builtin_amdgcn_mfma_f32_16x16x32_bf16(qf[1][kk], b, d[h][1][n], 0, 0, 0);
          d[h][2][n] = __builtin_amdgcn_mfma_f32_16x16x32_bf16(qf[2][kk], b, d[h][2][n], 0, 0, 0);
          d[h][3][n] = __builtin_amdgcn_mfma_f32_16x16x32_bf16(qf[3][kk], b, d[h][3][n], 0, 0, 0);
        }
      }
    }
    __builtin_amdgcn_s_setprio(0);

    // batched exp tail (both halves)
    #pragma unroll
    for (int h = 0; h < 2; ++h) {
      const float vsm0 = vs_lds[t * KVBLK + h * 32 + r16];
      const float vsm1 = vs_lds[t * KVBLK + h * 32 + 16 + r16];
      #pragma unroll
      for (int sub = 0; sub < 4; ++sub)
        #pragma unroll
        for (int j = 0; j < 4; ++j) {
          float e0 = fast_exp2(d[h][sub][0][j]);
          float e1 = fast_exp2(d[h][sub][1][j]);
          den[sub][j] += e0 + e1;
          acc[sub][j] = fmaf(e0, vsm0, fmaf(e1, vsm1, acc[sub][j]));
        }
    }
    __syncthreads();
  }

  #pragma unroll
  for (int sub = 0; sub < 4; ++sub)
    #pragma unroll
    for (int j = 0; j < 4; ++j) {
      #pragma unroll
      for (int off = 1; off < 16; off <<= 1) {
        den[sub][j] += __shfl_xor(den[sub][j], off);
        acc[sub][j] += __shfl_xor(acc[sub][j], off);
      }
    }
  if (r16 == 0) {
    #pragma unroll
    for (int sub = 0; sub < 4; ++sub)
      #pragma unroll
      for (int j = 0; j < 4; ++j) {
        int row = rowbase + sub * 16 + kg * 4 + j;
        pden[split * N_TOK + row] = den[sub][j];
        pacc[split * N_TOK + row] = acc[sub][j];
      }
  }
}

// ---------------- merge splits + residual ----------------
__global__ __launch_bounds__(256) void combine_kernel(
    const float* __restrict__ pden, const float* __restrict__ pacc,
    const float* __restrict__ hw2, const float* __restrict__ bv2, float* __restrict__ out)
{
  int r = blockIdx.x * 256 + threadIdx.x;
  float den = 0.f, acc = 0.f;
  #pragma unroll
  for (int s = 0; s < S_SPLIT; ++s) {
    den += pden[s * N_TOK + r];
    acc += pacc[s * N_TOK + r];
  }
  out[r] = hw2[r] + acc / den + bv2[0];
}

extern "C" void kernel_launch(void* const* d_in, const int* in_sizes, int n_in,
                              void* d_out, int out_size, void* d_ws, size_t ws_size,
                              hipStream_t stream) {
  const float* x      = (const float*)d_in[0];
  const float* lin1_w = (const float*)d_in[1];
  const float* lin1_b = (const float*)d_in[2];
  const float* q_w    = (const float*)d_in[3];
  const float* q_b    = (const float*)d_in[4];
  const float* k_w    = (const float*)d_in[5];
  const float* k_b    = (const float*)d_in[6];
  const float* v_w    = (const float*)d_in[7];
  const float* v_b    = (const float*)d_in[8];
  const float* lin2_w = (const float*)d_in[9];
  const float* lin2_b = (const float*)d_in[10];
  float* out = (float*)d_out;

  char* ws = (char*)d_ws;
  size_t off = 0;
  auto alloc = [&](size_t bytes) {
    char* p = ws + off;
    off += (bytes + 255) & ~(size_t)255;
    return p;
  };
  __hip_bfloat16* w1b = (__hip_bfloat16*)alloc((size_t)H_DIM * D_IN * 2);
  __hip_bfloat16* qwb = (__hip_bfloat16*)alloc((size_t)H_DIM * H_DIM * 2);
  __hip_bfloat16* kwb = (__hip_bfloat16*)alloc((size_t)H_DIM * H_DIM * 2);
  __hip_bfloat16* qb  = (__hip_bfloat16*)alloc((size_t)N_TOK * H_DIM * 2);
  __hip_bfloat16* kb  = (__hip_bfloat16*)alloc((size_t)N_TOK * H_DIM * 2);
  float* hw2  = (float*)alloc((size_t)N_TOK * 4);
  float* vsv  = (float*)alloc((size_t)N_TOK * 4);
  float* wv2  = (float*)alloc((size_t)H_DIM * 4);
  float* bv2  = (float*)alloc(256);
  float* pden = (float*)alloc((size_t)S_SPLIT * N_TOK * 4);
  float* pacc = (float*)alloc((size_t)S_SPLIT * N_TOK * 4);
  (void)ws_size; (void)in_sizes; (void)n_in; (void)out_size;

  prep_kernel<<<393, 256, 0, stream>>>(lin1_w, q_w, k_w, v_w, v_b, lin2_w,
                                       w1b, qwb, kwb, wv2, bv2);

  front_kernel<<<N_TOK / 32, 512, 0, stream>>>(x, w1b, qwb, kwb, lin1_b, q_b, k_b,
                                               lin2_w, wv2, lin2_b, qb, kb, hw2, vsv);

  attn_partial_kernel<<<dim3(32, S_SPLIT), 256, 0, stream>>>(qb, kb, vsv, pden, pacc);

  combine_kernel<<<N_TOK / 256, 256, 0, stream>>>(pden, pacc, hw2, bv2, out);
}